// Round 12
// baseline (96781.445 us; speedup 1.0000x reference)
//
#include <hip/hip_runtime.h>
#include <hip/hip_bf16.h>

#define S_LEN 4096
#define NTAG 24
#define START_TAG 22
#define STOP_TAG 23

// ---------------- ws layout (bytes) ----------------
static const size_t OFF_WT    = 0;                               // [300][2048] f32
static const size_t OFF_WHT   = OFF_WT + (size_t)300*2048*4;     // [2][256][1024] f32 (w_hh^T per dir)
static const size_t OFF_XG    = OFF_WHT + (size_t)2*256*1024*4;  // [2][4096][1024] f32 (dead after lstm)
static const size_t OFF_HS    = OFF_XG + (size_t)2*4096*1024*4;  // [2][4096][256] f32
static const size_t OFF_FEATS = OFF_HS + (size_t)2*4096*256*4;   // [4096][24] f32
static const size_t OFF_BP    = OFF_FEATS + (size_t)4096*24*4;   // [4096][24] u8 backpointers
static const size_t OFF_WALK  = OFF_XG;                          // [32][24][128] u8 (aliases XG)

__device__ __forceinline__ float sigf(float x) {
    return __fdividef(1.f, 1.f + __expf(-x));
}
__device__ __forceinline__ float tanhfast(float x) {
    return 1.f - __fdividef(2.f, 1.f + __expf(2.f * x));
}

// ---------------- prep: transpose W_ih and W_hh ----------------
__global__ void prep_kernel(const float* __restrict__ w_ih_f, const float* __restrict__ w_ih_b,
                            const float* __restrict__ w_hh_f, const float* __restrict__ w_hh_b,
                            float* __restrict__ WT, float* __restrict__ WHT) {
    int tid = blockIdx.x * blockDim.x + threadIdx.x;
    int nth = gridDim.x * blockDim.x;
    // WT[k][col]: col<1024 -> w_ih_f[col][k], else w_ih_b[col-1024][k]
    for (int idx = tid; idx < 300 * 2048; idx += nth) {
        int k = idx / 2048, col = idx % 2048;
        WT[idx] = (col < 1024) ? w_ih_f[col * 300 + k] : w_ih_b[(col - 1024) * 300 + k];
    }
    // WHT[d][k][row] = w_hh_d[row][k]
    for (int idx = tid; idx < 2 * 256 * 1024; idx += nth) {
        int d = idx >> 18;                 // 256*1024 = 2^18
        int rem = idx & ((1 << 18) - 1);
        int k = rem >> 10, row = rem & 1023;
        const float* w = d ? w_hh_b : w_hh_f;
        WHT[idx] = w[row * 256 + k];
    }
}

// ---------------- embed + input projection ----------------
__global__ __launch_bounds__(256) void embed_xg_kernel(const int* __restrict__ sentence,
                                                       const float* __restrict__ emb,
                                                       const float* __restrict__ WT,
                                                       const float* __restrict__ b_f,
                                                       const float* __restrict__ b_b,
                                                       float* __restrict__ xg) {
    __shared__ float xs[16][300];
    int s0 = blockIdx.x * 16;
    for (int idx = threadIdx.x; idx < 16 * 300; idx += 256) {
        int si = idx / 300, k = idx - si * 300;
        int wrow = sentence[s0 + si];
        xs[si][k] = emb[(size_t)wrow * 300 + k];
    }
    __syncthreads();
    for (int chunk = 0; chunk < 8; ++chunk) {
        int col = chunk * 256 + threadIdx.x;   // 0..2047
        float acc[16];
#pragma unroll
        for (int s = 0; s < 16; ++s) acc[s] = 0.f;
        for (int k = 0; k < 300; k += 4) {
            float w0 = WT[(k + 0) * 2048 + col];
            float w1 = WT[(k + 1) * 2048 + col];
            float w2 = WT[(k + 2) * 2048 + col];
            float w3 = WT[(k + 3) * 2048 + col];
#pragma unroll
            for (int s = 0; s < 16; ++s) {
                float4 x4 = *reinterpret_cast<const float4*>(&xs[s][k]);
                acc[s] += w0 * x4.x + w1 * x4.y + w2 * x4.z + w3 * x4.w;
            }
        }
        int dir = col >> 10;
        int row = col & 1023;
        float bias = dir ? b_b[row] : b_f[row];
#pragma unroll
        for (int s = 0; s < 16; ++s)
            xg[((size_t)dir * S_LEN + (s0 + s)) * 1024 + row] = acc[s] + bias;
    }
}

// ---------------- recurrent LSTM: ONE block per direction, zero cross-CU exchange ----------------
// 1024 threads; thread t owns gate row t: full W_hh row (256 f32) in VGPRs.
// h(t-1) in LDS hvec[256], read as 64 uniform ds_read_b128 (broadcast, conflict-free).
// No reduction (each thread completes its gate sum). Threads 0..255 do gate math, own c[t].
// Two barriers/step; no atomics, no sentinels, no spin loops -> cannot hang, no LLC RT.
__global__ __launch_bounds__(1024) void lstm_kernel(const float* __restrict__ xg,
                                                    const float* __restrict__ WHT,
                                                    float* __restrict__ hs) {
    const int dir = blockIdx.x;            // grid = 2
    const int t = threadIdx.x;             // gate row

    __shared__ float hvec[256];            // h(t-1)
    __shared__ float gl[1024];             // completed gate sums

    // weights: w[k] = WHT[dir][k][t]  (coalesced: consecutive t -> consecutive addr)
    float w[256];
    const float* wb = WHT + (size_t)dir * 256 * 1024 + t;
#pragma unroll
    for (int k = 0; k < 256; ++k) w[k] = wb[(size_t)k * 1024];

    if (t < 256) hvec[t] = 0.f;            // h(-1) = 0

    const float* xgd = xg + (size_t)dir * S_LEN * 1024;
    float* hsd = hs + (size_t)dir * S_LEN * 256;
    float c = 0.f;
    float xg_cur = xgd[(size_t)(dir ? (S_LEN - 1) : 0) * 1024 + t];
    __syncthreads();

    for (int step = 0; step < S_LEN; ++step) {
        const int st = dir ? (S_LEN - 1 - step) : step;

        // prefetch next step's xg (lands during the dot)
        float xg_nxt = 0.f;
        if (step + 1 < S_LEN) {
            const int stn = dir ? (st - 1) : (st + 1);
            xg_nxt = xgd[(size_t)stn * 1024 + t];
        }

        // ---- dot: full row, 64 x (uniform b128 LDS read + 4 FMA), 4 acc chains ----
        float a0 = 0.f, a1 = 0.f, a2 = 0.f, a3 = 0.f;
#pragma unroll
        for (int kb = 0; kb < 64; ++kb) {
            float4 h4 = *reinterpret_cast<const float4*>(&hvec[kb * 4]);
            a0 += w[kb * 4 + 0] * h4.x;
            a1 += w[kb * 4 + 1] * h4.y;
            a2 += w[kb * 4 + 2] * h4.z;
            a3 += w[kb * 4 + 3] * h4.w;
        }
        gl[t] = xg_cur + ((a0 + a1) + (a2 + a3));
        __syncthreads();                                   // B1: dots done, gl ready

        // ---- gates: threads 0..255 (c[t] persists per-thread) ----
        if (t < 256) {
            float gi = gl[t], gf = gl[256 + t], gg = gl[512 + t], go = gl[768 + t];
            c = sigf(gf) * c + sigf(gi) * tanhfast(gg);
            float h = sigf(go) * tanhfast(c);
            hvec[t] = h;
            hsd[(size_t)st * 256 + t] = h;                 // plain coalesced store
        }
        __syncthreads();                                   // B2: hvec(t) ready
        xg_cur = xg_nxt;
    }
}

// ---------------- feats = h @ w_tag^T + b_tag ----------------
__global__ __launch_bounds__(384) void feats_kernel(const float* __restrict__ hs,
                                                    const float* __restrict__ w_tag,
                                                    const float* __restrict__ b_tag,
                                                    float* __restrict__ feats) {
    __shared__ float ht[16][512];
    int s0 = blockIdx.x * 16;
    for (int idx = threadIdx.x; idx < 16 * 512; idx += 384) {
        int si = idx >> 9, k = idx & 511;
        float v = (k < 256) ? hs[(size_t)(s0 + si) * 256 + k]
                            : hs[(size_t)S_LEN * 256 + (size_t)(s0 + si) * 256 + (k - 256)];
        ht[si][k] = v;
    }
    __syncthreads();
    int si = threadIdx.x / NTAG;
    int t = threadIdx.x - si * NTAG;
    float acc = b_tag[t];
    const float* wr = w_tag + t * 512;
    for (int k = 0; k < 512; k += 4) {
        float4 w4 = *reinterpret_cast<const float4*>(&wr[k]);
        float4 h4 = *reinterpret_cast<const float4*>(&ht[si][k]);
        acc += w4.x * h4.x + w4.y * h4.y + w4.z * h4.z + w4.w * h4.w;
    }
    feats[(size_t)(s0 + si) * NTAG + t] = acc;
}

// ---------------- Viterbi: split-f forward (exact) + chunk-parallel backtrack (R8-proven) ----------------
__global__ __launch_bounds__(1024) void viterbi_kernel(const float* __restrict__ feats,
                                                       const float* __restrict__ trans,
                                                       unsigned char* __restrict__ bp_g,
                                                       unsigned char* __restrict__ walk_g,
                                                       float* __restrict__ out) {
    const int tid = threadIdx.x;
    __shared__ float s_bv;
    __shared__ int s_bti;
    __shared__ unsigned char maps[32][24];
    __shared__ int Bc[32];

    if (tid < 64) {
        const int lane = tid;
        const bool lo = lane < NTAG;
        const bool hi = (lane >= 32) && (lane < 32 + NTAG);
        const bool act = lo || hi;
        const int to = lo ? lane : lane - 32;
        const int fbase = lo ? 0 : 12;
        float wt[12];
#pragma unroll
        for (int j = 0; j < 12; ++j)
            wt[j] = act ? trans[to * NTAG + fbase + j] : -3.0e38f;
        float v = act ? ((to == START_TAG) ? 0.f : -10000.f) : -3.0e38f;
        float feat = act ? feats[to] : 0.f;

        for (int s = 0; s < S_LEN; ++s) {
            float featn = (act && s + 1 < S_LEN) ? feats[(s + 1) * NTAG + to] : 0.f;
            float m1 = -3.0e38f;
            int b1 = fbase;
#pragma unroll
            for (int j = 0; j < 12; ++j) {
                float cand = __shfl(v, fbase + j) + wt[j];   // v for tag f lives in lane f (0..23)
                if (cand > m1) { m1 = cand; b1 = fbase + j; } // first-max within half
            }
            float m2 = __shfl_xor(m1, 32);
            int b2 = __shfl_xor(b1, 32);
            float mlo = lo ? m1 : m2; int blo = lo ? b1 : b2;
            float mhi = lo ? m2 : m1; int bhi = lo ? b2 : b1;
            float m = fmaxf(mlo, mhi);
            int bi = (mhi > mlo) ? bhi : blo;                // tie -> lower f (first max)
            v = m + feat;
            if (lo) bp_g[s * NTAG + lane] = (unsigned char)bi;
            feat = featn;
        }
        float wstop = act ? trans[STOP_TAG * NTAG + to] : 0.f;
        float bv = lo ? (v + wstop) : -3.0e38f;
        int bti = lo ? lane : 64;
#pragma unroll
        for (int d = 1; d < 64; d <<= 1) {
            float ov = __shfl_xor(bv, d);
            int oi = __shfl_xor(bti, d);
            if (ov > bv || (ov == bv && oi < bti)) { bv = ov; bti = oi; }
        }
        if (lane == 0) { s_bv = bv; s_bti = bti; }
    }
    __syncthreads();

    if (tid < 32 * NTAG) {
        const int c = tid / NTAG, E = tid - c * NTAG;
        const unsigned char* bpc = bp_g + (size_t)c * 128 * NTAG;
        unsigned char* wk = walk_g + (size_t)(c * NTAG + E) * 128;
        int m = E;
        wk[127] = (unsigned char)m;
        for (int j = 126; j >= 0; --j) {
            m = bpc[(j + 1) * NTAG + m];
            wk[j] = (unsigned char)m;
        }
        maps[c][E] = bpc[m];
    }
    __syncthreads();

    if (tid == 0) {
        int t = s_bti;
        for (int c = 31; c >= 0; --c) {
            Bc[c] = t;
            if (c) t = maps[c][t];
        }
        out[0] = s_bv;
    }
    __syncthreads();

    for (int i = tid; i < S_LEN; i += 1024) {
        int c = i >> 7, j = i & 127;
        out[1 + i] = (float)walk_g[(size_t)(c * NTAG + Bc[c]) * 128 + j];
    }
}

// ---------------- launch ----------------
extern "C" void kernel_launch(void* const* d_in, const int* in_sizes, int n_in,
                              void* d_out, int out_size, void* d_ws, size_t ws_size,
                              hipStream_t stream) {
    const int*   sentence = (const int*)d_in[0];
    const float* emb      = (const float*)d_in[1];
    const float* w_ih_f   = (const float*)d_in[2];
    const float* w_hh_f   = (const float*)d_in[3];
    const float* b_f      = (const float*)d_in[4];
    const float* w_ih_b   = (const float*)d_in[5];
    const float* w_hh_b   = (const float*)d_in[6];
    const float* b_b      = (const float*)d_in[7];
    const float* w_tag    = (const float*)d_in[8];
    const float* b_tag    = (const float*)d_in[9];
    const float* trans    = (const float*)d_in[10];

    char* ws = (char*)d_ws;
    float*         WT    = (float*)(ws + OFF_WT);
    float*         WHT   = (float*)(ws + OFF_WHT);
    float*         XG    = (float*)(ws + OFF_XG);
    float*         HS    = (float*)(ws + OFF_HS);
    float*         FEATS = (float*)(ws + OFF_FEATS);
    unsigned char* BP    = (unsigned char*)(ws + OFF_BP);
    unsigned char* WALK  = (unsigned char*)(ws + OFF_WALK);   // aliases XG (dead after lstm)

    float* out = (float*)d_out;

    prep_kernel<<<512, 256, 0, stream>>>(w_ih_f, w_ih_b, w_hh_f, w_hh_b, WT, WHT);
    embed_xg_kernel<<<S_LEN / 16, 256, 0, stream>>>(sentence, emb, WT, b_f, b_b, XG);
    lstm_kernel<<<2, 1024, 0, stream>>>(XG, WHT, HS);
    feats_kernel<<<S_LEN / 16, 384, 0, stream>>>(HS, w_tag, b_tag, FEATS);
    viterbi_kernel<<<1, 1024, 0, stream>>>(FEATS, trans, BP, WALK, out);
}

// Round 13
// 8890.002 us; speedup vs baseline: 10.8865x; 10.8865x over previous
//
#include <hip/hip_runtime.h>
#include <hip/hip_bf16.h>

#define S_LEN 4096
#define NTAG 24
#define START_TAG 22
#define STOP_TAG 23
#define SENT 0x7F800001u

// ---------------- ws layout (bytes) ----------------
static const size_t OFF_WT    = 0;                               // [300][2048] f32
static const size_t OFF_XG    = OFF_WT + (size_t)300*2048*4;     // [2][4096][1024] f32 (dead after lstm; walk aliases it)
static const size_t OFF_HS    = OFF_XG + (size_t)2*4096*1024*4;  // [2][4096][256] f32
static const size_t OFF_FEATS = OFF_HS + (size_t)2*4096*256*4;   // [4096][24] f32
static const size_t OFF_BP    = OFF_FEATS + (size_t)4096*24*4;   // [4096][24] u8 backpointers
static const size_t OFF_WALK  = OFF_XG;                          // [32][24][128] u8 (aliases XG)

__device__ __forceinline__ float sigf(float x) {
    return __fdividef(1.f, 1.f + __expf(-x));
}
__device__ __forceinline__ float tanhfast(float x) {
    return 1.f - __fdividef(2.f, 1.f + __expf(2.f * x));
}

// R3-proven visibility mechanism: agent-scope atomic word store + word poll (LLC).
__device__ __forceinline__ float atomic_poll_word(const float* p) {
    float v;
    do {
        v = __hip_atomic_load(p, __ATOMIC_RELAXED, __HIP_MEMORY_SCOPE_AGENT);
    } while (__float_as_uint(v) == SENT);
    return v;
}

// ---------------- prep: transpose W_ih, sentinel-fill HS ----------------
__global__ void prep_kernel(const float* __restrict__ w_ih_f, const float* __restrict__ w_ih_b,
                            float* __restrict__ WT, unsigned int* __restrict__ HSu) {
    int tid = blockIdx.x * blockDim.x + threadIdx.x;
    int nth = gridDim.x * blockDim.x;
    for (int idx = tid; idx < 300 * 2048; idx += nth) {
        int k = idx / 2048, col = idx % 2048;
        WT[idx] = (col < 1024) ? w_ih_f[col * 300 + k] : w_ih_b[(col - 1024) * 300 + k];
    }
    // sentinel-fill hidden-state buffer — every launch (graph-replay safe)
    for (int idx = tid; idx < 2 * S_LEN * 256; idx += nth)
        HSu[idx] = SENT;
}

// ---------------- embed + input projection ----------------
__global__ __launch_bounds__(256) void embed_xg_kernel(const int* __restrict__ sentence,
                                                       const float* __restrict__ emb,
                                                       const float* __restrict__ WT,
                                                       const float* __restrict__ b_f,
                                                       const float* __restrict__ b_b,
                                                       float* __restrict__ xg) {
    __shared__ float xs[16][300];
    int s0 = blockIdx.x * 16;
    for (int idx = threadIdx.x; idx < 16 * 300; idx += 256) {
        int si = idx / 300, k = idx - si * 300;
        int wrow = sentence[s0 + si];
        xs[si][k] = emb[(size_t)wrow * 300 + k];
    }
    __syncthreads();
    for (int chunk = 0; chunk < 8; ++chunk) {
        int col = chunk * 256 + threadIdx.x;   // 0..2047
        float acc[16];
#pragma unroll
        for (int s = 0; s < 16; ++s) acc[s] = 0.f;
        for (int k = 0; k < 300; k += 4) {
            float w0 = WT[(k + 0) * 2048 + col];
            float w1 = WT[(k + 1) * 2048 + col];
            float w2 = WT[(k + 2) * 2048 + col];
            float w3 = WT[(k + 3) * 2048 + col];
#pragma unroll
            for (int s = 0; s < 16; ++s) {
                float4 x4 = *reinterpret_cast<const float4*>(&xs[s][k]);
                acc[s] += w0 * x4.x + w1 * x4.y + w2 * x4.z + w3 * x4.w;
            }
        }
        int dir = col >> 10;
        int row = col & 1023;
        float bias = dir ? b_b[row] : b_f[row];
#pragma unroll
        for (int s = 0; s < 16; ++s)
            xg[((size_t)dir * S_LEN + (s0 + s)) * 1024 + row] = acc[s] + bias;
    }
}

// ---------------- recurrent LSTM: broadcast-dot + slim reduce, R3 exchange, 2 barriers ----------------
// launch 64 blocks; only (id&7)<2 active: dir = id&7, rank = id>>3.
// Wave wv = (slice s = wv>>1, half hi = wv&1); lane l -> local row r = hi*64+l, k in [s*32,s*32+32).
// Dot reads hvec with wave-uniform addresses (LDS broadcast: ~2KB/step, no conflicts).
// part[128][9] (pad 9: 2-way conflicts only). Gate threads (wave 0, lanes 0..31) gather all
// 32 partials + prefetched xg, compute gates, agent-store h. Pollers waves 1..4 (R3 ops).
// hvec reads (pre-B1) and writes (post-B1) separated -> no R7 race. 2 barriers/step.
__global__ __launch_bounds__(1024) void lstm_kernel(const float* __restrict__ xg,
                                                    const float* __restrict__ w_hh_f,
                                                    const float* __restrict__ w_hh_b,
                                                    float* __restrict__ hs) {
    const int xslot = blockIdx.x & 7;
    if (xslot > 1) return;                 // 48 inert blocks exit
    const int dir = xslot;
    const int blk = blockIdx.x >> 3;       // 0..7
    const int tid = threadIdx.x;
    const int wv = tid >> 6;               // wave 0..15
    const int l  = tid & 63;               // lane
    const int s  = wv >> 1;                // k-slice 0..7 (32 k each)
    const int hi = wv & 1;                 // row half
    const int r  = hi * 64 + l;            // local row 0..127

    __shared__ float hvec[256];            // h(t-1), plain layout (uniform reads)
    __shared__ float part[128][9];         // 8 k-slice partials per local row (pad 9)

    const float* whh = dir ? w_hh_b : w_hh_f;   // [1024][256], row = g*256 + h_out
    // local row r = g*32 + j  ->  global row g*256 + blk*32 + j
    const int g = r >> 5, j = r & 31;
    const int grow = g * 256 + blk * 32 + j;
    float w[32];
#pragma unroll
    for (int i = 0; i < 32; ++i)
        w[i] = whh[(size_t)grow * 256 + s * 32 + i];

    for (int i = tid; i < 256; i += 1024) hvec[i] = 0.f;   // h(-1) = 0

    const float* xgd = xg + (size_t)dir * S_LEN * 1024;
    float* hsd = hs + (size_t)dir * S_LEN * 256;
    float c = 0.f;

    // gate threads: wave 0 lanes 0..31 -> h word blk*32+tid; xg rows g2*256+blk*32+tid
    const bool is_gate = (tid < 32);
    float xc0 = 0.f, xc1 = 0.f, xc2 = 0.f, xc3 = 0.f;
    if (is_gate) {
        const size_t b0 = (size_t)(dir ? (S_LEN - 1) : 0) * 1024 + blk * 32 + tid;
        xc0 = xgd[b0];
        xc1 = xgd[b0 + 256];
        xc2 = xgd[b0 + 512];
        xc3 = xgd[b0 + 768];
    }
    // pollers: tid 64..287 (waves 1..4), 224 remote words
    const bool is_pol = (tid >= 64 && tid < 288);
    int pol_w = 0;
    if (is_pol) {
        int idx = tid - 64;
        pol_w = idx + ((idx >= blk * 32) ? 32 : 0);
    }
    __syncthreads();

    for (int step = 0; step < S_LEN; ++step) {
        const int st = dir ? (S_LEN - 1 - step) : step;

        // prefetch next step's xg (gate threads; lands under dot)
        float xn0 = 0.f, xn1 = 0.f, xn2 = 0.f, xn3 = 0.f;
        if (is_gate && step + 1 < S_LEN) {
            const int stn = dir ? (st - 1) : (st + 1);
            const size_t bn = (size_t)stn * 1024 + blk * 32 + tid;
            xn0 = xgd[bn];
            xn1 = xgd[bn + 256];
            xn2 = xgd[bn + 512];
            xn3 = xgd[bn + 768];
        }

        // ---- dot: 32 MAC/thread, wave-uniform b128 hvec reads (broadcast) ----
        float a0 = 0.f, a1 = 0.f, a2 = 0.f, a3 = 0.f;
#pragma unroll
        for (int i4 = 0; i4 < 8; ++i4) {
            float4 h4 = *reinterpret_cast<const float4*>(&hvec[s * 32 + i4 * 4]);
            a0 += w[i4 * 4 + 0] * h4.x;
            a1 += w[i4 * 4 + 1] * h4.y;
            a2 += w[i4 * 4 + 2] * h4.z;
            a3 += w[i4 * 4 + 3] * h4.w;
        }
        part[r][s] = (a0 + a1) + (a2 + a3);
        __syncthreads();                                   // B1: partials ready, hvec reads done

        // ---- gate threads: gather 32 partials + xg, gates, publish ----
        if (is_gate) {
            float g0 = xc0, g1 = xc1, g2 = xc2, g3 = xc3;
#pragma unroll
            for (int ss = 0; ss < 8; ++ss) {
                g0 += part[tid][ss];
                g1 += part[32 + tid][ss];
                g2 += part[64 + tid][ss];
                g3 += part[96 + tid][ss];
            }
            c = sigf(g1) * c + sigf(g0) * tanhfast(g2);
            float h = sigf(g3) * tanhfast(c);
            __hip_atomic_store(&hsd[(size_t)st * 256 + blk * 32 + tid], h,
                               __ATOMIC_RELAXED, __HIP_MEMORY_SCOPE_AGENT);
            hvec[blk * 32 + tid] = h;                      // own slice -> LDS
        }
        // ---- pollers: remote 224 words (R3-proven agent-atomic spin) ----
        else if (is_pol && step + 1 < S_LEN) {
            float v = atomic_poll_word(&hsd[(size_t)st * 256 + pol_w]);
            hvec[pol_w] = v;
        }
        xc0 = xn0; xc1 = xn1; xc2 = xn2; xc3 = xn3;
        __syncthreads();                                   // B_end: hvec(t) complete
    }
}

// ---------------- feats = h @ w_tag^T + b_tag ----------------
__global__ __launch_bounds__(384) void feats_kernel(const float* __restrict__ hs,
                                                    const float* __restrict__ w_tag,
                                                    const float* __restrict__ b_tag,
                                                    float* __restrict__ feats) {
    __shared__ float ht[16][512];
    int s0 = blockIdx.x * 16;
    for (int idx = threadIdx.x; idx < 16 * 512; idx += 384) {
        int si = idx >> 9, k = idx & 511;
        float v = (k < 256) ? hs[(size_t)(s0 + si) * 256 + k]
                            : hs[(size_t)S_LEN * 256 + (size_t)(s0 + si) * 256 + (k - 256)];
        ht[si][k] = v;
    }
    __syncthreads();
    int si = threadIdx.x / NTAG;
    int t = threadIdx.x - si * NTAG;
    float acc = b_tag[t];
    const float* wr = w_tag + t * 512;
    for (int k = 0; k < 512; k += 4) {
        float4 w4 = *reinterpret_cast<const float4*>(&wr[k]);
        float4 h4 = *reinterpret_cast<const float4*>(&ht[si][k]);
        acc += w4.x * h4.x + w4.y * h4.y + w4.z * h4.z + w4.w * h4.w;
    }
    feats[(size_t)(s0 + si) * NTAG + t] = acc;
}

// ---------------- Viterbi: split-f forward (exact) + chunk-parallel backtrack (R8-proven) ----------------
__global__ __launch_bounds__(1024) void viterbi_kernel(const float* __restrict__ feats,
                                                       const float* __restrict__ trans,
                                                       unsigned char* __restrict__ bp_g,
                                                       unsigned char* __restrict__ walk_g,
                                                       float* __restrict__ out) {
    const int tid = threadIdx.x;
    __shared__ float s_bv;
    __shared__ int s_bti;
    __shared__ unsigned char maps[32][24];
    __shared__ int Bc[32];

    if (tid < 64) {
        const int lane = tid;
        const bool lo = lane < NTAG;
        const bool hi = (lane >= 32) && (lane < 32 + NTAG);
        const bool act = lo || hi;
        const int to = lo ? lane : lane - 32;
        const int fbase = lo ? 0 : 12;
        float wt[12];
#pragma unroll
        for (int j = 0; j < 12; ++j)
            wt[j] = act ? trans[to * NTAG + fbase + j] : -3.0e38f;
        float v = act ? ((to == START_TAG) ? 0.f : -10000.f) : -3.0e38f;
        float feat = act ? feats[to] : 0.f;

        for (int s = 0; s < S_LEN; ++s) {
            float featn = (act && s + 1 < S_LEN) ? feats[(s + 1) * NTAG + to] : 0.f;
            float m1 = -3.0e38f;
            int b1 = fbase;
#pragma unroll
            for (int j = 0; j < 12; ++j) {
                float cand = __shfl(v, fbase + j) + wt[j];   // v for tag f lives in lane f (0..23)
                if (cand > m1) { m1 = cand; b1 = fbase + j; } // first-max within half
            }
            float m2 = __shfl_xor(m1, 32);
            int b2 = __shfl_xor(b1, 32);
            float mlo = lo ? m1 : m2; int blo = lo ? b1 : b2;
            float mhi = lo ? m2 : m1; int bhi = lo ? b2 : b1;
            float m = fmaxf(mlo, mhi);
            int bi = (mhi > mlo) ? bhi : blo;                // tie -> lower f (first max)
            v = m + feat;
            if (lo) bp_g[s * NTAG + lane] = (unsigned char)bi;
            feat = featn;
        }
        float wstop = act ? trans[STOP_TAG * NTAG + to] : 0.f;
        float bv = lo ? (v + wstop) : -3.0e38f;
        int bti = lo ? lane : 64;
#pragma unroll
        for (int d = 1; d < 64; d <<= 1) {
            float ov = __shfl_xor(bv, d);
            int oi = __shfl_xor(bti, d);
            if (ov > bv || (ov == bv && oi < bti)) { bv = ov; bti = oi; }
        }
        if (lane == 0) { s_bv = bv; s_bti = bti; }
    }
    __syncthreads();

    if (tid < 32 * NTAG) {
        const int c = tid / NTAG, E = tid - c * NTAG;
        const unsigned char* bpc = bp_g + (size_t)c * 128 * NTAG;
        unsigned char* wk = walk_g + (size_t)(c * NTAG + E) * 128;
        int m = E;
        wk[127] = (unsigned char)m;
        for (int j = 126; j >= 0; --j) {
            m = bpc[(j + 1) * NTAG + m];
            wk[j] = (unsigned char)m;
        }
        maps[c][E] = bpc[m];
    }
    __syncthreads();

    if (tid == 0) {
        int t = s_bti;
        for (int c = 31; c >= 0; --c) {
            Bc[c] = t;
            if (c) t = maps[c][t];
        }
        out[0] = s_bv;
    }
    __syncthreads();

    for (int i = tid; i < S_LEN; i += 1024) {
        int c = i >> 7, j = i & 127;
        out[1 + i] = (float)walk_g[(size_t)(c * NTAG + Bc[c]) * 128 + j];
    }
}

// ---------------- launch ----------------
extern "C" void kernel_launch(void* const* d_in, const int* in_sizes, int n_in,
                              void* d_out, int out_size, void* d_ws, size_t ws_size,
                              hipStream_t stream) {
    const int*   sentence = (const int*)d_in[0];
    const float* emb      = (const float*)d_in[1];
    const float* w_ih_f   = (const float*)d_in[2];
    const float* w_hh_f   = (const float*)d_in[3];
    const float* b_f      = (const float*)d_in[4];
    const float* w_ih_b   = (const float*)d_in[5];
    const float* w_hh_b   = (const float*)d_in[6];
    const float* b_b      = (const float*)d_in[7];
    const float* w_tag    = (const float*)d_in[8];
    const float* b_tag    = (const float*)d_in[9];
    const float* trans    = (const float*)d_in[10];

    char* ws = (char*)d_ws;
    float*         WT    = (float*)(ws + OFF_WT);
    float*         XG    = (float*)(ws + OFF_XG);
    float*         HS    = (float*)(ws + OFF_HS);
    float*         FEATS = (float*)(ws + OFF_FEATS);
    unsigned char* BP    = (unsigned char*)(ws + OFF_BP);
    unsigned char* WALK  = (unsigned char*)(ws + OFF_WALK);   // aliases XG (dead after lstm)

    float* out = (float*)d_out;

    prep_kernel<<<512, 256, 0, stream>>>(w_ih_f, w_ih_b, WT, (unsigned int*)HS);
    embed_xg_kernel<<<S_LEN / 16, 256, 0, stream>>>(sentence, emb, WT, b_f, b_b, XG);
    lstm_kernel<<<64, 1024, 0, stream>>>(XG, w_hh_f, w_hh_b, HS);
    feats_kernel<<<S_LEN / 16, 384, 0, stream>>>(HS, w_tag, b_tag, FEATS);
    viterbi_kernel<<<1, 1024, 0, stream>>>(FEATS, trans, BP, WALK, out);
}